// Round 13
// baseline (1276.731 us; speedup 1.0000x reference)
//
#include <hip/hip_runtime.h>
#include <hip/hip_bf16.h>
#include <stdint.h>

using bf16 = __hip_bfloat16;
typedef __bf16 bf16x8 __attribute__((ext_vector_type(8)));
typedef unsigned int u32x4 __attribute__((ext_vector_type(4)));
typedef float f32x4 __attribute__((ext_vector_type(4)));

#define GLOAD_LDS16(gp, lp)                                                    \
  __builtin_amdgcn_global_load_lds(                                           \
      (const __attribute__((address_space(1))) void*)(gp),                     \
      (__attribute__((address_space(3))) void*)(lp), 16, 0, 0)

#define WAITCNT_VM(N) asm volatile("s_waitcnt vmcnt(" #N ")" ::: "memory")
#define WAITCNT_LGKM0() asm volatile("s_waitcnt lgkmcnt(0)" ::: "memory")
#define SB0() __builtin_amdgcn_sched_barrier(0)

__device__ inline void store_out(bf16* p, float v)  { *p = __float2bfloat16(v); }
__device__ inline void store_out(float* p, float v) { *p = v; }

__device__ __forceinline__ bf16x8 ldsread16(const bf16* p) {
    u32x4 r = *reinterpret_cast<const u32x4*>(p);
    return __builtin_bit_cast(bf16x8, r);
}

// ---------------------------------------------------------------------------
// NT GEMM, 256x256 tile, BK=64 (2 K-halves of 32), m201-faithful 8-phase
// schedule. Port-saturation design (r12 model: LDS port util is the governing
// resource; 8-wave barrier groups + 16-MFMA phases keep it ~90% busy):
//   phase(H,kh) = m-half H x K-half kh: reads A 4 ds_read (+B 4 when H==0,
//   B-frags reused across H), stage ONE K-half (2 gload_lds), 2 barriers.
//   MFMA issue (~64cy) doesn't wait for completion -> waves re-feed the port.
// Stage/sync proof: pair q = (tile q>>1, khalf q&1), 4-slot LDS ring
// (slot q&3). Consumed at phases 2q,2q+1; staged at 2q-4,2q-3 (one half per
// phase). vmcnt(4) at EVERY phase close leaves the last 2 stages outstanding
// => the pair consumed next phase is drained (incl. prologue; tail peels to
// vmcnt(2)/vmcnt(0)). WAR: slot last read 3+ phases (w/ barriers) before its
// restage. 512 thr = 8 waves (2M x 4N), wave out 128x64 (acc 8x4 f32x4).
// C[m][n] = alpha*sum_k A[m][k]*Bt[n][k] (+bias). Col-split epilogue.
// BIAS_AXIS: 0 per-col, 1 per-row. M,N mult 256; K mult 64, K/64 >= 2.
// LDS 128 KB: A slots s*8192 elems, B at 32768+s*8192 (s=0..3; 256 rows x
// 32 k each). Swizzle (0-conflict, r9-verified): chunk col c of row r stored
// at c^((r>>1)&3); read elem = row*32 + ((c16^((fr>>1)&3))<<3).
// ---------------------------------------------------------------------------
template <typename OUT_T, int BIAS_AXIS, bool NFAST>
__global__ __launch_bounds__(512, 2) void gemm8p(
    const bf16* __restrict__ A, const bf16* __restrict__ Bt,
    const float* __restrict__ bias0, const float* __restrict__ bias1,
    OUT_T* __restrict__ out0, OUT_T* __restrict__ out1, int Nsplit,
    int K, int lda, int ldb, int ldc,
    long long sA, long long sB, long long sC, float alpha)
{
    __shared__ __align__(16) bf16 lds[65536];   // 128 KB

    // ---- T1: chunked XCD swizzle + logical tile decode
    const int Mt = gridDim.x, Nt = gridDim.y;
    const int nwg = Mt * Nt * gridDim.z;
    const int hw  = blockIdx.x + Mt * (blockIdx.y + Nt * blockIdx.z);
    const int lg  = (nwg & 7) ? hw : ((hw & 7) * (nwg >> 3) + (hw >> 3));
    const int per = Mt * Nt;
    const int zt  = lg / per;
    const int rem = lg - zt * per;
    int mt, nt;
    if (NFAST) { mt = rem / Nt; nt = rem - mt * Nt; }
    else       { mt = rem % Mt; nt = rem / Mt; }

    A  += (long long)zt * sA;
    Bt += (long long)zt * sB;
    out0 += (long long)zt * sC;
    if (out1) out1 += (long long)zt * sC;

    const int bm = mt * 256, bn = nt * 256;
    const int t = threadIdx.x, lane = t & 63, w = t >> 6;
    const int wm = w >> 2, wn = w & 3;            // 2M x 4N waves
    const int fr = lane & 15, c16 = lane >> 4;

    // ---- staging: thread t stages chunks {t, t+512} of each 256x32 K-half
    const bf16* gA[2];
    const bf16* gB[2];
    #pragma unroll
    for (int k = 0; k < 2; ++k) {
        const int idx = t + 512 * k, r = idx >> 2, c = idx & 3;
        const int cs = (c ^ ((r >> 1) & 3)) << 3;
        gA[k] = A  + (long long)(bm + r) * lda + cs;
        gB[k] = Bt + (long long)(bn + r) * ldb + cs;
    }
    const int d0 = t * 8, d1 = t * 8 + 4096;

#define STG_A(T1, KH, SBASE) do {                                              \
    GLOAD_LDS16(gA[0] + (T1) * 64 + (KH) * 32, &lds[(SBASE) + d0]);            \
    GLOAD_LDS16(gA[1] + (T1) * 64 + (KH) * 32, &lds[(SBASE) + d1]);            \
} while (0)
#define STG_B(T1, KH, SBASE) do {                                              \
    GLOAD_LDS16(gB[0] + (T1) * 64 + (KH) * 32, &lds[32768 + (SBASE) + d0]);    \
    GLOAD_LDS16(gB[1] + (T1) * 64 + (KH) * 32, &lds[32768 + (SBASE) + d1]);    \
} while (0)

    // ---- fragment read offsets (swizzled, 0-conflict involution)
    const int swz  = (c16 ^ ((fr >> 1) & 3)) << 3;
    const int offA0 = (wm * 128 + fr) * 32 + swz;          // + mf*512
    const int offB0 = (wn * 64 + fr) * 32 + swz;           // + nf*512 (B base)

    f32x4 acc[8][4] = {};
    bf16x8 af[4], bfv[4];

#define RDA(H, SBASE) do {                                                     \
    _Pragma("unroll") for (int mf = 0; mf < 4; ++mf)                           \
        af[mf] = ldsread16(&lds[(SBASE) + offA0 + ((H) * 4 + mf) * 512]);      \
} while (0)
#define RDB(SBASE) do {                                                        \
    _Pragma("unroll") for (int nf = 0; nf < 4; ++nf)                           \
        bfv[nf] = ldsread16(&lds[32768 + (SBASE) + offB0 + nf * 512]);         \
} while (0)
#define MM(H) do {                                                             \
    _Pragma("unroll") for (int mf = 0; mf < 4; ++mf)                           \
        _Pragma("unroll") for (int nf = 0; nf < 4; ++nf)                       \
            acc[(H) * 4 + mf][nf] = __builtin_amdgcn_mfma_f32_16x16x32_bf16(   \
                af[mf], bfv[nf], acc[(H) * 4 + mf][nf], 0, 0, 0);              \
} while (0)
#define PH_MID(H) do {                                                         \
    SB0(); __builtin_amdgcn_s_barrier();                                       \
    WAITCNT_LGKM0(); SB0();                                                    \
    __builtin_amdgcn_s_setprio(1); MM(H); __builtin_amdgcn_s_setprio(0);       \
} while (0)
#define PH_END() do { __builtin_amdgcn_s_barrier(); } while (0)

    const int nk = K >> 6;          // K-tiles of 64, >= 2

    // prologue: stage pairs 0,1 (tile 0 both K-halves); drain pair 0
    STG_A(0, 0, 0); STG_B(0, 0, 0);
    STG_A(0, 1, 8192); STG_B(0, 1, 8192);
    WAITCNT_VM(4);
    __builtin_amdgcn_s_barrier();

    for (int T = 0; T < nk; ++T) {
        const int sb = (T & 1) << 14;   // this tile's k0 slot base (A-rel)
        const int so = sb ^ 16384;      // staged tile's k0 slot base
        if (T + 1 < nk) {
            // p0: (H0,k0) reads A0-3+B, stages A-k0(T+1)
            RDA(0, sb); RDB(sb); STG_A(T + 1, 0, so);
            PH_MID(0); WAITCNT_VM(4); PH_END();
            // p1: (H1,k0), stages B-k0(T+1)
            RDA(1, sb); STG_B(T + 1, 0, so);
            PH_MID(1); WAITCNT_VM(4); PH_END();
            // p2: (H0,k1) reads A+B of k1, stages A-k1(T+1)
            RDA(0, sb + 8192); RDB(sb + 8192); STG_A(T + 1, 1, so + 8192);
            PH_MID(0); WAITCNT_VM(4); PH_END();
            // p3: (H1,k1), stages B-k1(T+1)
            RDA(1, sb + 8192); STG_B(T + 1, 1, so + 8192);
            PH_MID(1); WAITCNT_VM(4); PH_END();
        } else {
            // tail tile: no stages; drain remaining pair progressively
            RDA(0, sb); RDB(sb);
            PH_MID(0); WAITCNT_VM(2); PH_END();
            RDA(1, sb);
            PH_MID(1); WAITCNT_VM(0); PH_END();
            RDA(0, sb + 8192); RDB(sb + 8192);
            PH_MID(0); PH_END();
            RDA(1, sb + 8192);
            PH_MID(1);
        }
    }

    // ---- epilogue: C/D layout col = lane&15, row = 4*(lane>>4)+reg
    const int colbase = bn + wn * 64 + fr;
    const int rowbase = bm + wm * 128 + c16 * 4;
    #pragma unroll
    for (int n = 0; n < 4; ++n) {
        const int gc = colbase + n * 16;
        const bool seg0 = gc < Nsplit;
        OUT_T* op = seg0 ? out0 : out1;
        const int col = seg0 ? gc : gc - Nsplit;
        float bcol = 0.0f;
        if (BIAS_AXIS == 0) {
            const float* bp = seg0 ? bias0 : bias1;
            if (bp) bcol = bp[col];
        }
        #pragma unroll
        for (int m = 0; m < 8; ++m) {
            #pragma unroll
            for (int jj = 0; jj < 4; ++jj) {
                const int row = rowbase + m * 16 + jj;
                float v = acc[m][n][jj] * alpha;
                if (BIAS_AXIS == 0) v += bcol;
                else if (bias0)     v += bias0[row];
                store_out(&op[(long long)row * ldc + col], v);
            }
        }
    }
#undef STG_A
#undef STG_B
#undef RDA
#undef RDB
#undef MM
#undef PH_MID
#undef PH_END
}

// ---------------------------------------------------------------------------
__global__ __launch_bounds__(256) void f32_to_bf16(
    const float* __restrict__ in, bf16* __restrict__ out, long long n)
{
    long long i = ((long long)blockIdx.x * 256 + threadIdx.x) * 4;
    const long long stride = (long long)gridDim.x * 256 * 4;
    for (; i < n; i += stride) {
        float4 v = *reinterpret_cast<const float4*>(in + i);
        unsigned ux = __float_as_uint(v.x), uy = __float_as_uint(v.y);
        unsigned uz = __float_as_uint(v.z), uw = __float_as_uint(v.w);
        ushort4 o;
        o.x = (unsigned short)((ux + 0x7fffu + ((ux >> 16) & 1u)) >> 16);
        o.y = (unsigned short)((uy + 0x7fffu + ((uy >> 16) & 1u)) >> 16);
        o.z = (unsigned short)((uz + 0x7fffu + ((uz >> 16) & 1u)) >> 16);
        o.w = (unsigned short)((uw + 0x7fffu + ((uw >> 16) & 1u)) >> 16);
        *reinterpret_cast<ushort4*>(out + i) = o;
    }
}

__global__ void transpose_f32_bf16(const float* __restrict__ in,
                                   bf16* __restrict__ out, int R, int C)
{
    __shared__ float tile[32][33];
    const int c0 = blockIdx.x * 32, r0 = blockIdx.y * 32;
    const int tx = threadIdx.x, ty = threadIdx.y;
    #pragma unroll
    for (int i = ty; i < 32; i += 8)
        tile[i][tx] = in[(long long)(r0 + i) * C + (c0 + tx)];
    __syncthreads();
    #pragma unroll
    for (int i = ty; i < 32; i += 8)
        out[(long long)(c0 + i) * R + (r0 + tx)] = __float2bfloat16(tile[tx][i]);
}

__global__ __launch_bounds__(256) void softmax_rows(bf16* __restrict__ Sbuf, int cols)
{
    __shared__ float red[8];
    bf16* p = Sbuf + (long long)blockIdx.x * cols;
    const int t = threadIdx.x;

    u32x4 v = *reinterpret_cast<const u32x4*>(p + t * 8);
    float f[8];
    #pragma unroll
    for (int i = 0; i < 4; ++i) {
        f[2 * i]     = __uint_as_float(v[i] << 16);
        f[2 * i + 1] = __uint_as_float(v[i] & 0xffff0000u);
    }

    float m = -3.0e38f;
    #pragma unroll
    for (int i = 0; i < 8; ++i) m = fmaxf(m, f[i]);
    #pragma unroll
    for (int o = 32; o; o >>= 1) m = fmaxf(m, __shfl_xor(m, o));
    if ((t & 63) == 0) red[t >> 6] = m;
    __syncthreads();
    m = fmaxf(fmaxf(red[0], red[1]), fmaxf(red[2], red[3]));

    float s = 0.0f;
    #pragma unroll
    for (int i = 0; i < 8; ++i) { f[i] = __expf(f[i] - m); s += f[i]; }
    #pragma unroll
    for (int o = 32; o; o >>= 1) s += __shfl_xor(s, o);
    __syncthreads();
    if ((t & 63) == 0) red[4 + (t >> 6)] = s;
    __syncthreads();
    s = (red[4] + red[5]) + (red[6] + red[7]);
    const float inv = 1.0f / s;

    u32x4 o16;
    #pragma unroll
    for (int i = 0; i < 4; ++i) {
        unsigned ua = __float_as_uint(f[2 * i] * inv);
        unsigned ub = __float_as_uint(f[2 * i + 1] * inv);
        ua = (ua + 0x7fffu + ((ua >> 16) & 1u)) >> 16;
        ub = (ub + 0x7fffu + ((ub >> 16) & 1u)) & 0xffff0000u;
        o16[i] = ua | ub;
    }
    *reinterpret_cast<u32x4*>(p + t * 8) = o16;
}

// ---------------------------------------------------------------------------
extern "C" void kernel_launch(void* const* d_in, const int* in_sizes, int n_in,
                              void* d_out, int out_size, void* d_ws, size_t ws_size,
                              hipStream_t stream)
{
    const int B = 8, S = 2048, D = 1024, H = 1024;
    const float* x  = (const float*)d_in[0];
    const float* Wq = (const float*)d_in[1];
    const float* bq = (const float*)d_in[2];
    const float* Wk = (const float*)d_in[3];
    const float* bk = (const float*)d_in[4];
    const float* Wv = (const float*)d_in[5];
    const float* bv = (const float*)d_in[6];
    float* out = (float*)d_out;

    const size_t nQKV = (size_t)B * S * H;
    const size_t nW   = (size_t)D * H;
    const long long sSH = (long long)S * H;
    const long long sSS = (long long)S * S;

    dim3 tb(32, 8), g256(256), g512(512);
    const float inv_scale = 1.0f / 32.0f;    // 1/sqrt(H)

    // ws: xb | Q | K | Vt | WtQK(2nW) | Wtv(nW) | Sc
    bf16* xb   = (bf16*)d_ws;
    bf16* Q    = xb  + nQKV;
    bf16* Kb   = Q   + nQKV;
    bf16* Vt   = Kb  + nQKV;                 // [H][B*S], ld = B*S
    bf16* WtQK = Vt  + nQKV;
    bf16* Wtv  = WtQK + 2 * nW;
    bf16* Sc   = Wtv + nW;

    const size_t tierA = (4 * nQKV + 3 * nW + (size_t)B * S * S) * 2;
    const size_t tierB = (4 * nQKV + 3 * nW + (size_t)S * S) * 2;
    const bool bigA = ws_size >= tierA;
    if (ws_size < tierB) return;

    // 1. convert x; transpose weights
    f32_to_bf16<<<dim3(2048), g256, 0, stream>>>(x, xb, (long long)nQKV);
    transpose_f32_bf16<<<dim3(H / 32, D / 32), tb, 0, stream>>>(Wq, WtQK, D, H);
    transpose_f32_bf16<<<dim3(H / 32, D / 32), tb, 0, stream>>>(Wk, WtQK + nW, D, H);
    transpose_f32_bf16<<<dim3(H / 32, D / 32), tb, 0, stream>>>(Wv, Wtv, D, H);

    // 2. fused Q|K projection: [16384,1024] x [2048,1024]^T, col-split
    gemm8p<bf16, 0, true><<<dim3(B * S / 256, 2 * H / 256, 1), g512, 0, stream>>>(
        xb, WtQK, bq, bk, Q, Kb, H, D, D, D, H, 0, 0, 0, 1.0f);

    // 3. V^T = Wv^T x^T : A=Wtv [H][D], Bt=xb [B*S][D] -> Vt [H][B*S]
    gemm8p<bf16, 1, false><<<dim3(H / 256, B * S / 256, 1), g512, 0, stream>>>(
        Wtv, xb, bv, nullptr, Vt, nullptr, 1 << 30, D, D, D, B * S, 0, 0, 0, 1.0f);

    if (bigA) {
        // 4. scores = Q K^T / 32, batched
        gemm8p<bf16, 0, true><<<dim3(S / 256, S / 256, B), g512, 0, stream>>>(
            Q, Kb, nullptr, nullptr, Sc, nullptr, 1 << 30, H, H, H, S,
            sSH, sSH, sSS, inv_scale);
        // 5. softmax rows in place
        softmax_rows<<<dim3(B * S), g256, 0, stream>>>(Sc, S);
        // 6. out = P V
        gemm8p<float, 0, true><<<dim3(S / 256, H / 256, B), g512, 0, stream>>>(
            Sc, Vt, nullptr, nullptr, out, nullptr, 1 << 30, S, S, B * S, H,
            sSS, (long long)S, sSH, 1.0f);
    } else {
        for (int b = 0; b < B; ++b) {
            gemm8p<bf16, 0, true><<<dim3(S / 256, S / 256, 1), g512, 0, stream>>>(
                Q + (size_t)b * sSH, Kb + (size_t)b * sSH, nullptr, nullptr,
                Sc, nullptr, 1 << 30, H, H, H, S, 0, 0, 0, inv_scale);
            softmax_rows<<<dim3(S), g256, 0, stream>>>(Sc, S);
            gemm8p<float, 0, true><<<dim3(S / 256, H / 256, 1), g512, 0, stream>>>(
                Sc, Vt + (size_t)b * S, nullptr, nullptr,
                out + (size_t)b * sSH, nullptr, 1 << 30, S, S, B * S, H,
                0, 0, 0, 1.0f);
        }
    }
}

// Round 14
// 336.398 us; speedup vs baseline: 3.7953x; 3.7953x over previous
//
#include <hip/hip_runtime.h>
#include <hip/hip_bf16.h>
#include <stdint.h>

using bf16 = __hip_bfloat16;
typedef __bf16 bf16x8 __attribute__((ext_vector_type(8)));
typedef unsigned int u32x4 __attribute__((ext_vector_type(4)));
typedef float f32x4 __attribute__((ext_vector_type(4)));
typedef float f32x16 __attribute__((ext_vector_type(16)));

#define GLOAD_LDS16(gp, lp)                                                    \
  __builtin_amdgcn_global_load_lds(                                           \
      (const __attribute__((address_space(1))) void*)(gp),                     \
      (__attribute__((address_space(3))) void*)(lp), 16, 0, 0)

#define WAITCNT_VM(N) asm volatile("s_waitcnt vmcnt(" #N ")" ::: "memory")
#define SB0() __builtin_amdgcn_sched_barrier(0)

__device__ inline void store_out(bf16* p, float v)  { *p = __float2bfloat16(v); }
__device__ inline void store_out(float* p, float v) { *p = v; }

__device__ __forceinline__ bf16x8 ldsread16(const bf16* p) {
    u32x4 r = *reinterpret_cast<const u32x4*>(p);
    return __builtin_bit_cast(bf16x8, r);
}

// ---------------------------------------------------------------------------
// NT GEMM, 256x128 tile, BK=32, ring-3 LDS (72 KB -> 2 blocks/CU), counted
// vmcnt (T4), 0-conflict swizzled LDS (T2), T1 chunked-XCD swizzle.
// == round-12 structure (best measured: 818 TF) with ONE change: MFMA shape
// 16x16x32 -> 32x32x16 (ubench 2075 -> 2495 TF, +21% pipe efficiency; halves
// MFMA instruction count per step: 16 x 32kFLOP vs 32 x 16kFLOP).
// 256 thr = 4 waves (2M x 2N), per-wave 128x64 out = 4x2 frags of 32x32
// (acc f32x16 x8 = 128 AGPR, static-indexed).
// C[m][n] = alpha * sum_k A[m][k]*Bt[n][k] (+bias). Col-split epilogue.
// BIAS_AXIS: 0 per-col, 1 per-row. M mult 256, N mult 128, K mult 32 (>=64).
//
// LDS: 3 ring slots x 12288 elems (A 256x32 at +0, B 128x32 at +8192).
// Chunk (16B): row r, chunk col c stored at c ^ ((r>>1)&3)  [r12-measured
// 0 conflicts; 32x32 read pattern is bank-isomorphic: 4-chunk XOR spread,
// hi-half lanes on disjoint chunk cols].
// Frag addressing (32x32x16): A row = l31 (+mf*32), k = s*16 + hi*8
//   -> chunk c = 2s+hi, elem = row*32 + ((2s+hi)^((row>>1)&3))*8.
// C/D layout [m74/m101]: col = lane&31, row = (reg&3)+8*(reg>>2)+4*hi.
//
// Sync per step j (unchanged from r12): [12 ds_read_b128 (slot j%3); stage
// tile j+2 (6 gloads); 16 MFMA; vmcnt(6); s_barrier]. RAW: outstanding at
// step end = st(j+1) 6 + st(j+2) 6; vmcnt(6) drains st(j+1). WAR: st(j+2)
// targets slot of tile j-1, consumed before its closing barrier.
// ---------------------------------------------------------------------------
template <typename OUT_T, int BIAS_AXIS, bool NFAST>
__global__ __launch_bounds__(256, 2) void gemm_bm(
    const bf16* __restrict__ A, const bf16* __restrict__ Bt,
    const float* __restrict__ bias0, const float* __restrict__ bias1,
    OUT_T* __restrict__ out0, OUT_T* __restrict__ out1, int Nsplit,
    int K, int lda, int ldb, int ldc,
    long long sA, long long sB, long long sC, float alpha)
{
    __shared__ __align__(16) bf16 lds[36864];   // 72 KB: 3 x (8192 A + 4096 B)

    // ---- T1: chunked XCD swizzle + logical tile decode
    const int Mt = gridDim.x, Nt = gridDim.y;
    const int nwg = Mt * Nt * gridDim.z;
    const int hw  = blockIdx.x + Mt * (blockIdx.y + Nt * blockIdx.z);
    const int lg  = (nwg & 7) ? hw : ((hw & 7) * (nwg >> 3) + (hw >> 3));
    const int per = Mt * Nt;
    const int zt  = lg / per;
    const int rem = lg - zt * per;
    int mt, nt;
    if (NFAST) { mt = rem / Nt; nt = rem - mt * Nt; }
    else       { mt = rem % Mt; nt = rem / Mt; }

    A  += (long long)zt * sA;
    Bt += (long long)zt * sB;
    out0 += (long long)zt * sC;
    if (out1) out1 += (long long)zt * sC;

    const int bm = mt * 256;
    const int bn = nt * 128;
    const int t = threadIdx.x, lane = t & 63, w = t >> 6;
    const int wm = w >> 1, wn = w & 1;            // wave grid 2M x 2N
    const int l31 = lane & 31, hi = lane >> 5;

    // ---- staging src pointers: A chunks {t+256k, k<4}, B chunks {t+256k, k<2}
    const bf16* gA[4];
    const bf16* gB[2];
    #pragma unroll
    for (int k = 0; k < 4; ++k) {
        const int idx = t + 256 * k, r = idx >> 2, c = idx & 3;
        gA[k] = A + (long long)(bm + r) * lda + ((c ^ ((r >> 1) & 3)) << 3);
    }
    #pragma unroll
    for (int k = 0; k < 2; ++k) {
        const int idx = t + 256 * k, r = idx >> 2, c = idx & 3;
        gB[k] = Bt + (long long)(bn + r) * ldb + ((c ^ ((r >> 1) & 3)) << 3);
    }
    const int dstA = t * 8;            // + k*2048, elem offset in slot
    const int dstB = 8192 + t * 8;     // + k*2048

#define STAGE(JT, SLOTB) do {                                                  \
    GLOAD_LDS16(gA[0] + (JT) * 32, &lds[(SLOTB) + dstA]);                      \
    GLOAD_LDS16(gA[1] + (JT) * 32, &lds[(SLOTB) + dstA + 2048]);               \
    GLOAD_LDS16(gA[2] + (JT) * 32, &lds[(SLOTB) + dstA + 4096]);               \
    GLOAD_LDS16(gA[3] + (JT) * 32, &lds[(SLOTB) + dstA + 6144]);               \
    GLOAD_LDS16(gB[0] + (JT) * 32, &lds[(SLOTB) + dstB]);                      \
    GLOAD_LDS16(gB[1] + (JT) * 32, &lds[(SLOTB) + dstB + 2048]);               \
} while (0)

    // ---- fragment read offsets (32x32x16, swizzled)
    const int rowA = wm * 128 + l31;              // + mf*32
    const int rowB = wn * 64 + l31;               // + fn*32
    const int sAx = (rowA >> 1) & 3, sBx = (rowB >> 1) & 3;
    const int aB0 = rowA * 32;                    // elem base (A region)
    const int bB0 = 8192 + rowB * 32;             // elem base (B region)
    int ak[2], bk[2];
    #pragma unroll
    for (int s = 0; s < 2; ++s) {
        ak[s] = ((2 * s + hi) ^ sAx) << 3;
        bk[s] = ((2 * s + hi) ^ sBx) << 3;
    }

    const int nk = K >> 5;

    // prologue: stage tiles 0,1; drain tile 0 (keep 6 in flight)
    STAGE(0, 0); STAGE(1, 12288);
    WAITCNT_VM(6);
    __builtin_amdgcn_s_barrier();

    f32x16 acc[4][2] = {};

    int slotb = 0;
    for (int j = 0; j < nk; ++j) {
        SB0();   // region open

        bf16x8 af[4][2], bf[2][2];
        #pragma unroll
        for (int mf = 0; mf < 4; ++mf)
            #pragma unroll
            for (int s = 0; s < 2; ++s)
                af[mf][s] = ldsread16(&lds[slotb + aB0 + mf * 1024 + ak[s]]);
        #pragma unroll
        for (int fn = 0; fn < 2; ++fn)
            #pragma unroll
            for (int s = 0; s < 2; ++s)
                bf[fn][s] = ldsread16(&lds[slotb + bB0 + fn * 1024 + bk[s]]);

        if (j + 2 < nk) {
            int s2 = slotb + 24576; if (s2 >= 36864) s2 -= 36864;
            STAGE(j + 2, s2);
        }

        #pragma unroll
        for (int s = 0; s < 2; ++s)
            #pragma unroll
            for (int mf = 0; mf < 4; ++mf)
                #pragma unroll
                for (int fn = 0; fn < 2; ++fn)
                    acc[mf][fn] = __builtin_amdgcn_mfma_f32_32x32x16_bf16(
                        af[mf][s], bf[fn][s], acc[mf][fn], 0, 0, 0);

        SB0();   // region close
        if (j + 2 < nk)      { WAITCNT_VM(6); }
        else if (j + 1 < nk) { WAITCNT_VM(0); }
        __builtin_amdgcn_s_barrier();

        slotb += 12288; if (slotb == 36864) slotb = 0;
    }

    // ---- epilogue: 32x32 C/D: col = lane&31, row = (reg&3)+8*(reg>>2)+4*hi
    const int colb = bn + wn * 64 + l31;
    const int rowb = bm + wm * 128 + hi * 4;
    #pragma unroll
    for (int fn = 0; fn < 2; ++fn) {
        const int gc = colb + fn * 32;
        const bool seg0 = gc < Nsplit;
        OUT_T* op = seg0 ? out0 : out1;
        const int col = seg0 ? gc : gc - Nsplit;
        float bcol = 0.0f;
        if (BIAS_AXIS == 0) {
            const float* bp = seg0 ? bias0 : bias1;
            if (bp) bcol = bp[col];
        }
        #pragma unroll
        for (int mf = 0; mf < 4; ++mf) {
            #pragma unroll
            for (int q = 0; q < 4; ++q) {
                #pragma unroll
                for (int jj = 0; jj < 4; ++jj) {
                    const int row = rowb + mf * 32 + jj + 8 * q;
                    float v = acc[mf][fn][q * 4 + jj] * alpha;
                    if (BIAS_AXIS == 0) v += bcol;
                    else if (bias0)     v += bias0[row];
                    store_out(&op[(long long)row * ldc + col], v);
                }
            }
        }
    }
#undef STAGE
}

// ---------------------------------------------------------------------------
// fp32 -> bf16 elementwise convert (n multiple of 4)
// ---------------------------------------------------------------------------
__global__ __launch_bounds__(256) void f32_to_bf16(
    const float* __restrict__ in, bf16* __restrict__ out, long long n)
{
    long long i = ((long long)blockIdx.x * 256 + threadIdx.x) * 4;
    const long long stride = (long long)gridDim.x * 256 * 4;
    for (; i < n; i += stride) {
        float4 v = *reinterpret_cast<const float4*>(in + i);
        unsigned ux = __float_as_uint(v.x), uy = __float_as_uint(v.y);
        unsigned uz = __float_as_uint(v.z), uw = __float_as_uint(v.w);
        ushort4 o;
        o.x = (unsigned short)((ux + 0x7fffu + ((ux >> 16) & 1u)) >> 16);
        o.y = (unsigned short)((uy + 0x7fffu + ((uy >> 16) & 1u)) >> 16);
        o.z = (unsigned short)((uz + 0x7fffu + ((uz >> 16) & 1u)) >> 16);
        o.w = (unsigned short)((uw + 0x7fffu + ((uw >> 16) & 1u)) >> 16);
        *reinterpret_cast<ushort4*>(out + i) = o;
    }
}

// ---------------------------------------------------------------------------
// Transpose fp32 in [R][C] -> bf16 out [C][R]
// ---------------------------------------------------------------------------
__global__ void transpose_f32_bf16(const float* __restrict__ in,
                                   bf16* __restrict__ out, int R, int C)
{
    __shared__ float tile[32][33];
    const int c0 = blockIdx.x * 32, r0 = blockIdx.y * 32;
    const int tx = threadIdx.x, ty = threadIdx.y;
    #pragma unroll
    for (int i = ty; i < 32; i += 8)
        tile[i][tx] = in[(long long)(r0 + i) * C + (c0 + tx)];
    __syncthreads();
    #pragma unroll
    for (int i = ty; i < 32; i += 8)
        out[(long long)(c0 + i) * R + (r0 + tx)] = __float2bfloat16(tile[tx][i]);
}

// ---------------------------------------------------------------------------
// Row softmax, in-place on bf16 buffer, one 256-thread block per 2048-col row.
// ---------------------------------------------------------------------------
__global__ __launch_bounds__(256) void softmax_rows(bf16* __restrict__ Sbuf, int cols)
{
    __shared__ float red[8];
    bf16* p = Sbuf + (long long)blockIdx.x * cols;
    const int t = threadIdx.x;

    u32x4 v = *reinterpret_cast<const u32x4*>(p + t * 8);
    float f[8];
    #pragma unroll
    for (int i = 0; i < 4; ++i) {
        f[2 * i]     = __uint_as_float(v[i] << 16);
        f[2 * i + 1] = __uint_as_float(v[i] & 0xffff0000u);
    }

    float m = -3.0e38f;
    #pragma unroll
    for (int i = 0; i < 8; ++i) m = fmaxf(m, f[i]);
    #pragma unroll
    for (int o = 32; o; o >>= 1) m = fmaxf(m, __shfl_xor(m, o));
    if ((t & 63) == 0) red[t >> 6] = m;
    __syncthreads();
    m = fmaxf(fmaxf(red[0], red[1]), fmaxf(red[2], red[3]));

    float s = 0.0f;
    #pragma unroll
    for (int i = 0; i < 8; ++i) { f[i] = __expf(f[i] - m); s += f[i]; }
    #pragma unroll
    for (int o = 32; o; o >>= 1) s += __shfl_xor(s, o);
    __syncthreads();
    if ((t & 63) == 0) red[4 + (t >> 6)] = s;
    __syncthreads();
    s = (red[4] + red[5]) + (red[6] + red[7]);
    const float inv = 1.0f / s;

    u32x4 o16;
    #pragma unroll
    for (int i = 0; i < 4; ++i) {
        unsigned ua = __float_as_uint(f[2 * i] * inv);
        unsigned ub = __float_as_uint(f[2 * i + 1] * inv);
        ua = (ua + 0x7fffu + ((ua >> 16) & 1u)) >> 16;
        ub = (ub + 0x7fffu + ((ub >> 16) & 1u)) & 0xffff0000u;
        o16[i] = ua | ub;
    }
    *reinterpret_cast<u32x4*>(p + t * 8) = o16;
}

// ---------------------------------------------------------------------------
extern "C" void kernel_launch(void* const* d_in, const int* in_sizes, int n_in,
                              void* d_out, int out_size, void* d_ws, size_t ws_size,
                              hipStream_t stream)
{
    const int B = 8, S = 2048, D = 1024, H = 1024;
    const float* x  = (const float*)d_in[0];
    const float* Wq = (const float*)d_in[1];
    const float* bq = (const float*)d_in[2];
    const float* Wk = (const float*)d_in[3];
    const float* bk = (const float*)d_in[4];
    const float* Wv = (const float*)d_in[5];
    const float* bv = (const float*)d_in[6];
    float* out = (float*)d_out;

    const size_t nQKV = (size_t)B * S * H;
    const size_t nW   = (size_t)D * H;
    const long long sSH = (long long)S * H;
    const long long sSS = (long long)S * S;

    dim3 tb(32, 8), g256(256);
    const float inv_scale = 1.0f / 32.0f;    // 1/sqrt(H)

    // ws: xb | Q | K | Vt | WtQK(2nW) | Wtv(nW) | Sc
    bf16* xb   = (bf16*)d_ws;
    bf16* Q    = xb  + nQKV;
    bf16* Kb   = Q   + nQKV;
    bf16* Vt   = Kb  + nQKV;                 // [H][B*S], ld = B*S
    bf16* WtQK = Vt  + nQKV;
    bf16* Wtv  = WtQK + 2 * nW;
    bf16* Sc   = Wtv + nW;

    const size_t tierA = (4 * nQKV + 3 * nW + (size_t)B * S * S) * 2;
    const size_t tierB = (4 * nQKV + 3 * nW + (size_t)S * S) * 2;
    const bool bigA = ws_size >= tierA;
    if (ws_size < tierB) return;

    // 1. convert x; transpose weights
    f32_to_bf16<<<dim3(2048), g256, 0, stream>>>(x, xb, (long long)nQKV);
    transpose_f32_bf16<<<dim3(H / 32, D / 32), tb, 0, stream>>>(Wq, WtQK, D, H);
    transpose_f32_bf16<<<dim3(H / 32, D / 32), tb, 0, stream>>>(Wk, WtQK + nW, D, H);
    transpose_f32_bf16<<<dim3(H / 32, D / 32), tb, 0, stream>>>(Wv, Wtv, D, H);

    // 2. fused Q|K projection: [B*S,1024] x [2048,1024]^T -> Q, K (col-split)
    gemm_bm<bf16, 0, true><<<dim3(B * S / 256, 2 * H / 128, 1), g256, 0, stream>>>(
        xb, WtQK, bq, bk, Q, Kb, H, D, D, D, H, 0, 0, 0, 1.0f);

    // 3. V^T = Wv^T x^T : A=Wtv [H][D], Bt=xb [B*S][D] -> Vt [H][B*S], bias-by-row
    gemm_bm<bf16, 1, false><<<dim3(H / 256, B * S / 128, 1), g256, 0, stream>>>(
        Wtv, xb, bv, nullptr, Vt, nullptr, 1 << 30, D, D, D, B * S, 0, 0, 0, 1.0f);

    if (bigA) {
        // 4. scores = Q K^T / 32, batched
        gemm_bm<bf16, 0, true><<<dim3(S / 256, S / 128, B), g256, 0, stream>>>(
            Q, Kb, nullptr, nullptr, Sc, nullptr, 1 << 30, H, H, H, S,
            sSH, sSH, sSS, inv_scale);
        // 5. softmax rows in place
        softmax_rows<<<dim3(B * S), g256, 0, stream>>>(Sc, S);
        // 6. out = P V
        gemm_bm<float, 0, true><<<dim3(S / 256, H / 128, B), g256, 0, stream>>>(
            Sc, Vt, nullptr, nullptr, out, nullptr, 1 << 30, S, S, B * S, H,
            sSS, (long long)S, sSH, 1.0f);
    } else {
        for (int b = 0; b < B; ++b) {
            gemm_bm<bf16, 0, true><<<dim3(S / 256, S / 128, 1), g256, 0, stream>>>(
                Q + (size_t)b * sSH, Kb + (size_t)b * sSH, nullptr, nullptr,
                Sc, nullptr, 1 << 30, H, H, H, S, 0, 0, 0, inv_scale);
            softmax_rows<<<dim3(S), g256, 0, stream>>>(Sc, S);
            gemm_bm<float, 0, true><<<dim3(S / 256, H / 128, 1), g256, 0, stream>>>(
                Sc, Vt + (size_t)b * S, nullptr, nullptr,
                out + (size_t)b * sSH, nullptr, 1 << 30, S, S, B * S, H,
                0, 0, 0, 1.0f);
        }
    }
}